// Round 10
// baseline (10344.080 us; speedup 1.0000x reference)
//
#include <hip/hip_runtime.h>
#include <hip/hip_bf16.h>
#include <math.h>

// Decoder with attention: V=32000 E=512 H=1024 B=64 S=128 T=65 (NT=64 steps)
#define BATCH 64
#define SRC   128
#define HID   1024
#define EMB   512
#define NT    64
#define G4    4096   // 4H

__device__ __forceinline__ float sigmoidf_(float x){ return 1.0f/(1.0f+expf(-x)); }

// ===================== skinny GEMM (precompute hh_term partials) =====================
__launch_bounds__(256, 2)
__global__ void skinny_gemm(const float* __restrict__ A, int lda,
                            const float* __restrict__ W, int ldw,
                            float* __restrict__ partial, int N, int Kchunk){
  const int nc = blockIdx.x;
  const int kc = blockIdx.y;
  const int kbase = kc * Kchunk;
  const int tid = threadIdx.x;
  __shared__ float As[16][68];
  __shared__ float Bs[16][132];
  const int wave = tid >> 6, lane = tid & 63;
  const int lm = lane & 7, ln = lane >> 3;
  const int nwave = nc*128 + wave*32;
  float acc[8][4] = {};
  const int arow = tid >> 2, akc = (tid & 3) * 4;
  for (int k0 = 0; k0 < Kchunk; k0 += 16){
    int kg = kbase + k0 + akc;
    float4 av = *(const float4*)(A + (size_t)arow*lda + kg);
    As[akc+0][arow]=av.x; As[akc+1][arow]=av.y; As[akc+2][arow]=av.z; As[akc+3][arow]=av.w;
    #pragma unroll
    for (int r = 0; r < 2; ++r){
      int idx = tid + r*256;
      int nrow = idx >> 2, bkc = (idx & 3) * 4;
      float4 wv = *(const float4*)(W + (size_t)(nc*128 + nrow)*ldw + kbase + k0 + bkc);
      Bs[bkc+0][nrow]=wv.x; Bs[bkc+1][nrow]=wv.y; Bs[bkc+2][nrow]=wv.z; Bs[bkc+3][nrow]=wv.w;
    }
    __syncthreads();
    #pragma unroll
    for (int k = 0; k < 16; ++k){
      float4 alo = *(const float4*)&As[k][lm*8];
      float4 ahi = *(const float4*)&As[k][lm*8+4];
      float4 b4  = *(const float4*)&Bs[k][wave*32 + ln*4];
      float am[8] = {alo.x,alo.y,alo.z,alo.w,ahi.x,ahi.y,ahi.z,ahi.w};
      float bn[4] = {b4.x,b4.y,b4.z,b4.w};
      #pragma unroll
      for (int i=0;i<8;++i)
        #pragma unroll
        for (int j=0;j<4;++j)
          acc[i][j] += am[i]*bn[j];
    }
    __syncthreads();
  }
  for (int i=0;i<8;++i){
    int m = lm*8+i;
    float4 v = make_float4(acc[i][0],acc[i][1],acc[i][2],acc[i][3]);
    *(float4*)(partial + ((size_t)(kc*64 + m))*N + nwave + ln*4) = v;
  }
}

// ===================== big GEMM 128x128 (precompute enc_proj / encW) =====================
__launch_bounds__(256, 2)
__global__ void big_gemm128(const float* __restrict__ A, int lda,
                            const float* __restrict__ W, int ldw,
                            float* __restrict__ C, int N, int K){
  const int n0 = blockIdx.x * 128;
  const int m0 = blockIdx.y * 128;
  const int tid = threadIdx.x;
  __shared__ float As[16][132];
  __shared__ float Bs[16][132];
  const int wave = tid >> 6, lane = tid & 63;
  const int wm = wave >> 1, wn = wave & 1;
  const int lm = lane & 7, ln = lane >> 3;
  float acc[8][8] = {};
  for (int k0 = 0; k0 < K; k0 += 16){
    #pragma unroll
    for (int r = 0; r < 2; ++r){
      int idx = tid + r*256;
      int row = idx >> 2, kq = (idx & 3) * 4;
      float4 av = *(const float4*)(A + (size_t)(m0+row)*lda + k0 + kq);
      As[kq+0][row]=av.x; As[kq+1][row]=av.y; As[kq+2][row]=av.z; As[kq+3][row]=av.w;
      float4 wv = *(const float4*)(W + (size_t)(n0+row)*ldw + k0 + kq);
      Bs[kq+0][row]=wv.x; Bs[kq+1][row]=wv.y; Bs[kq+2][row]=wv.z; Bs[kq+3][row]=wv.w;
    }
    __syncthreads();
    #pragma unroll
    for (int k = 0; k < 16; ++k){
      float4 a0 = *(const float4*)&As[k][wm*64 + lm*8];
      float4 a1 = *(const float4*)&As[k][wm*64 + lm*8 + 4];
      float4 b0 = *(const float4*)&Bs[k][wn*64 + ln*8];
      float4 b1 = *(const float4*)&Bs[k][wn*64 + ln*8 + 4];
      float am[8] = {a0.x,a0.y,a0.z,a0.w,a1.x,a1.y,a1.z,a1.w};
      float bn[8] = {b0.x,b0.y,b0.z,b0.w,b1.x,b1.y,b1.z,b1.w};
      #pragma unroll
      for (int i=0;i<8;++i)
        #pragma unroll
        for (int j=0;j<8;++j)
          acc[i][j] += am[i]*bn[j];
    }
    __syncthreads();
  }
  for (int i=0;i<8;++i){
    int m = m0 + wm*64 + lm*8 + i;
    float* cp = C + (size_t)m*N + n0 + wn*64 + ln*8;
    *(float4*)cp     = make_float4(acc[i][0],acc[i][1],acc[i][2],acc[i][3]);
    *(float4*)(cp+4) = make_float4(acc[i][4],acc[i][5],acc[i][6],acc[i][7]);
  }
}

__global__ void hh_reduce_kernel(const float* __restrict__ partial,
                                 const float* __restrict__ b_ih, const float* __restrict__ b_hh,
                                 float* __restrict__ hh_term){
  int g = blockIdx.x*512 + threadIdx.x;   // 64*4096
  int n = g & 4095;
  int b = g >> 12;
  float s = b_ih[n] + b_hh[n];
  #pragma unroll
  for (int kc=0; kc<8; ++kc) s += partial[((size_t)(kc*64+b))*G4 + n];
  hh_term[g] = s;
}

// WcT[k][j] = W_comb[j][k] for j,k < 1024 (h-part, transposed for lane-contiguous reads)
__global__ void transpose_wc(const float* __restrict__ W_comb, float* __restrict__ WcT){
  __shared__ float tile[32][33];
  int bx = blockIdx.x, by = blockIdx.y;           // k-tile, j-tile
  int tx = threadIdx.x & 31, ty = threadIdx.x >> 5; // 32 x 8
  int j0 = by*32, k0 = bx*32;
  #pragma unroll
  for (int r = 0; r < 4; ++r)
    tile[ty + r*8][tx] = W_comb[(size_t)(j0 + ty + r*8)*3072 + k0 + tx];
  __syncthreads();
  #pragma unroll
  for (int r = 0; r < 4; ++r)
    WcT[(size_t)(k0 + ty + r*8)*1024 + j0 + tx] = tile[tx][ty + r*8];
}

// Wgp[blk][k][rr] = W_ih[(rr&3)*1024 + blk*4 + (rr>>2)][k]  (packed for broadcast float4 reads)
__global__ void pack_wih(const float* __restrict__ W_ih, float* __restrict__ Wgp){
  int blk = blockIdx.x;           // 256
  int tid = threadIdx.x;          // 256
  for (int rr = 0; rr < 16; ++rr){
    int row = (rr & 3)*1024 + blk*4 + (rr >> 2);
    for (int k = tid; k < 1536; k += 256)
      Wgp[((size_t)blk*1536 + k)*16 + rr] = W_ih[(size_t)row*1536 + k];
  }
}

__global__ void init_kernel(float* __restrict__ O0){
  int i = blockIdx.x*512 + threadIdx.x;
  if (i < BATCH*HID) O0[i] = 0.f;
}

// ===================== K1: gates GEMM + LSTM -> h + e-partials =====================
// 256 blocks x 512 threads. Block blk owns h-cols j0=blk*4 (16 gate rows).
__global__ __launch_bounds__(512, 1)
void k1_gates_h_epart(const int* __restrict__ tgt, int t,
                      const float* __restrict__ emb, const float* __restrict__ Oprev,
                      const float* __restrict__ Wgp, const float* __restrict__ hh_term,
                      const float* __restrict__ dic, const float* __restrict__ enc_proj,
                      float* __restrict__ hbuf, float* __restrict__ e_part){
  const int blk = blockIdx.x, tid = threadIdx.x;
  const int wave = tid >> 6, lane = tid & 63;
  const int bg = lane >> 2, rg = lane & 3;     // 16 b-groups x 4 r-groups
  const int j0 = blk * 4;
  const float* wgp = Wgp + (size_t)blk*1536*16;

  __shared__ float scratch[8704];    // ybar chunk [128 k][68 b]; reused for partials
  __shared__ float hs[64][4];
  __shared__ int   toks[64];

  if (tid < 64) toks[tid] = tgt[t*BATCH + tid];
  __syncthreads();

  float acc[4][4] = {};
  for (int c = 0; c < 12; ++c){
    { // stage ybar chunk k-major
      int b = tid & 63, kq = tid >> 6;
      #pragma unroll
      for (int i = 0; i < 4; ++i){
        int kg = c*128 + kq*16 + i*4;
        float4 v;
        if (kg < EMB) v = *(const float4*)(emb + (size_t)toks[b]*EMB + kg);
        else          v = *(const float4*)(Oprev + b*HID + (kg - EMB));
        int kb = kq*16 + i*4;
        scratch[(kb+0)*68 + b] = v.x;
        scratch[(kb+1)*68 + b] = v.y;
        scratch[(kb+2)*68 + b] = v.z;
        scratch[(kb+3)*68 + b] = v.w;
      }
    }
    __syncthreads();
    #pragma unroll
    for (int kk = 0; kk < 16; ++kk){
      int k = wave*16 + kk;
      float4 yb = *(const float4*)&scratch[k*68 + bg*4];
      float4 wv = *(const float4*)(wgp + (size_t)(c*128 + k)*16 + rg*4);
      float ym[4] = {yb.x, yb.y, yb.z, yb.w};
      float wn[4] = {wv.x, wv.y, wv.z, wv.w};
      #pragma unroll
      for (int i = 0; i < 4; ++i)
        #pragma unroll
        for (int j = 0; j < 4; ++j)
          acc[i][j] += ym[i] * wn[j];
    }
    __syncthreads();
  }
  // wave partials -> [w][rr][b]
  #pragma unroll
  for (int i = 0; i < 4; ++i)
    #pragma unroll
    for (int j = 0; j < 4; ++j)
      scratch[wave*1024 + (rg*4 + j)*64 + bg*4 + i] = acc[i][j];
  __syncthreads();
  if (tid < 256){
    int b = tid & 63, jj = tid >> 6;
    float g4[4];
    #pragma unroll
    for (int g = 0; g < 4; ++g){
      float s = hh_term[b*G4 + g*1024 + j0 + jj];
      #pragma unroll
      for (int w = 0; w < 8; ++w) s += scratch[w*1024 + (jj*4 + g)*64 + b];
      g4[g] = s;
    }
    float c_ = sigmoidf_(g4[1]) * dic[b*HID + j0 + jj] + sigmoidf_(g4[0]) * tanhf(g4[2]);
    float h = sigmoidf_(g4[3]) * tanhf(c_);
    hbuf[b*HID + j0 + jj] = h;
    hs[b][jj] = h;
  }
  __syncthreads();
  // e_part[blk][b][s] = sum_{c=0..3} enc_proj[b][s][j0+c] * hs[b][c]
  for (int idx = tid; idx < BATCH*SRC; idx += 512){
    int b = idx >> 7, s = idx & 127;
    float4 ep = *(const float4*)(enc_proj + ((size_t)(b*SRC + s))*HID + j0);
    float4 hv = *(const float4*)&hs[b][0];
    e_part[(size_t)blk*BATCH*SRC + idx] = ep.x*hv.x + ep.y*hv.y + ep.z*hv.z + ep.w*hv.w;
  }
}

// ===================== K2: e-reduce + softmax + comb_h + comb_a + tanh + out =====================
// grid (64 b, 4 nq) x 512 threads.
__global__ __launch_bounds__(512, 1)
void k2_soft_comb(const float* __restrict__ e_part, const int* __restrict__ enc_mask,
                  const float* __restrict__ hbuf, const float* __restrict__ WcT,
                  const float* __restrict__ encW, float* __restrict__ out, int t){
  const int b = blockIdx.x, nq = blockIdx.y;
  const int tid = threadIdx.x;
  __shared__ float hsh[HID];
  __shared__ float er[4][SRC];
  __shared__ float red[SRC];
  __shared__ float al_s[SRC];
  __shared__ float ch[2][256];

  for (int i = tid; i < HID; i += 512) hsh[i] = hbuf[b*HID + i];

  // e-reduce: 4 groups x 128 s; each thread sums 64 jc-partials
  {
    int s = tid & 127, g = tid >> 7;
    const float* epb = e_part + (size_t)g*64*BATCH*SRC + b*SRC + s;
    float sum = 0.f;
    #pragma unroll 8
    for (int i = 0; i < 64; ++i) sum += epb[(size_t)i*BATCH*SRC];
    er[g][s] = sum;
  }
  __syncthreads();
  // masked softmax over 128
  float ev = -1e30f;
  if (tid < SRC){
    ev = er[0][tid] + er[1][tid] + er[2][tid] + er[3][tid];
    if (enc_mask[b*SRC + tid] != 0) ev = -1e30f;
    red[tid] = ev;
  }
  __syncthreads();
  for (int off=64; off>=1; off>>=1){ if (tid<off) red[tid]=fmaxf(red[tid],red[tid+off]); __syncthreads(); }
  float mval = red[0]; __syncthreads();
  float p = (tid < SRC) ? expf(ev - mval) : 0.f;
  if (tid < SRC) red[tid] = p;
  __syncthreads();
  for (int off=64; off>=1; off>>=1){ if (tid<off) red[tid]+=red[tid+off]; __syncthreads(); }
  if (tid < SRC) al_s[tid] = p / red[0];
  __syncthreads();

  // comb_h: col j = nq*256 + (tid&255), K split in halves over kh = tid>>8
  {
    int jc = tid & 255, kh = tid >> 8;
    int j = nq*256 + jc;
    const float* wct = WcT + (size_t)(kh*512)*HID + j;
    const float* hp  = &hsh[kh*512];
    float acc = 0.f;
    #pragma unroll 8
    for (int k = 0; k < 512; ++k) acc += hp[k] * wct[(size_t)k*HID];
    ch[kh][jc] = acc;
  }
  __syncthreads();

  // comb_a + tanh + write (256 threads)
  if (tid < 256){
    int j = nq*256 + tid;
    const float* ew = encW + (size_t)b*SRC*HID + j;
    float a_ = 0.f;
    #pragma unroll 8
    for (int s = 0; s < SRC; ++s) a_ += al_s[s] * ew[(size_t)s*HID];
    float v = tanhf(a_ + ch[0][tid] + ch[1][tid]);
    out[((size_t)t*BATCH + b)*HID + j] = v;
  }
}

extern "C" void kernel_launch(void* const* d_in, const int* in_sizes, int n_in,
                              void* d_out, int out_size, void* d_ws, size_t ws_size,
                              hipStream_t stream) {
  const int*   tgt        = (const int*)d_in[0];
  const float* enc_hidden = (const float*)d_in[1];
  const int*   enc_mask   = (const int*)d_in[2];
  const float* dih        = (const float*)d_in[3];
  const float* dic        = (const float*)d_in[4];
  const float* emb        = (const float*)d_in[5];
  const float* W_ih       = (const float*)d_in[6];
  const float* W_hh       = (const float*)d_in[7];
  const float* b_ih       = (const float*)d_in[8];
  const float* b_hh       = (const float*)d_in[9];
  const float* W_att      = (const float*)d_in[10];
  const float* W_comb     = (const float*)d_in[11];
  float* out = (float*)d_out;

  float* ws        = (float*)d_ws;
  float* enc_proj  = ws;                          // 8192*1024  = 8,388,608
  float* encW      = enc_proj + 8388608;          // 8192*1024  = 8,388,608
  float* hh_term   = encW + 8388608;              // 64*4096    =   262,144
  float* WcT       = hh_term + 262144;            // 1024*1024  = 1,048,576
  float* Wgp       = WcT + 1048576;               // 256*1536*16= 6,291,456
  float* e_part    = Wgp + 6291456;               // 256*64*128 = 2,097,152
  float* hbuf      = e_part + 2097152;            // 64*1024    =    65,536
  float* O0        = hbuf + 65536;                // 64*1024    =    65,536
  float* pg        = e_part;                      // precompute scratch (aliased, pre-step only)

  // ---- precompute ----
  big_gemm128<<<dim3(8,64), 256, 0, stream>>>(enc_hidden, 2048, W_att, 2048, enc_proj, HID, 2048);
  big_gemm128<<<dim3(8,64), 256, 0, stream>>>(enc_hidden, 2048, W_comb + HID, 3072, encW, HID, 2048);
  skinny_gemm<<<dim3(32,8), 256, 0, stream>>>(dih, HID, W_hh, HID, pg, G4, 128);
  hh_reduce_kernel<<<dim3(512), 512, 0, stream>>>(pg, b_ih, b_hh, hh_term);
  transpose_wc<<<dim3(32,32), 256, 0, stream>>>(W_comb, WcT);
  pack_wih<<<dim3(256), 256, 0, stream>>>(W_ih, Wgp);
  init_kernel<<<dim3(128), 512, 0, stream>>>(O0);

  // ---- 64 decode steps, 2 kernels each ----
  for (int t = 0; t < NT; ++t){
    const float* Oprev = (t == 0) ? O0 : out + (size_t)(t-1)*BATCH*HID;
    k1_gates_h_epart<<<dim3(256), 512, 0, stream>>>(
        tgt, t, emb, Oprev, Wgp, hh_term, dic, enc_proj, hbuf, e_part);
    k2_soft_comb<<<dim3(64,4), 512, 0, stream>>>(
        e_part, enc_mask, hbuf, WcT, encW, out, t);
  }
}